// Round 4
// baseline (8629.984 us; speedup 1.0000x reference)
//
#include <hip/hip_runtime.h>
#include <stdint.h>

// All-fp32 pipeline (bf16 fails: LN amplifies attention error x55, tan(delta)
// physics is chaotic near |delta|=pi/2 -> need fp32-accurate delta).

__device__ __forceinline__ float readlane_f(float v, int lane) {
  return __uint_as_float(__builtin_amdgcn_readlane(__float_as_uint(v), lane));
}
typedef __attribute__((ext_vector_type(4))) float f32x4;

// ---------------------------------------------------------------------------
// Kernel A: fused QKV projection (fp32). obs(8192x128) @ {Wq,Wk,Wv}(128x512)+b
// ---------------------------------------------------------------------------
__global__ __launch_bounds__(256) void qkv_f32(
    const float* __restrict__ obs,
    const float* __restrict__ Wq, const float* __restrict__ bq,
    const float* __restrict__ Wk, const float* __restrict__ bk,
    const float* __restrict__ Wv, const float* __restrict__ bv,
    float* __restrict__ Qf, float* __restrict__ Kf, float* __restrict__ Vf)
{
  __shared__ float smA[32][128];
  __shared__ float smB[64][128];
  const int t  = threadIdx.x;
  const int cb = blockIdx.x;
  const int rb = blockIdx.y;
  const float* W; const float* bias; float* Op;
  if (cb < 4)      { W = Wq; bias = bq; Op = Qf; }
  else if (cb < 8) { W = Wk; bias = bk; Op = Kf; }
  else             { W = Wv; bias = bv; Op = Vf; }
  const int col0 = (cb & 3) * 128;

  {
    const float4* src = (const float4*)(obs + (size_t)rb * (32 * 128));
    float4* dst = (float4*)&smA[0][0];
#pragma unroll
    for (int i = 0; i < 4; ++i) dst[i * 256 + t] = src[i * 256 + t];
  }

  const int tr = t >> 5, tc = t & 31;
  float acc[4][4] = {};
#pragma unroll 1
  for (int kc = 0; kc < 2; ++kc) {
    __syncthreads();
#pragma unroll
    for (int i = 0; i < 8; ++i) {
      int id = i * 256 + t;
      int kr = id >> 5, c4 = id & 31;
      *(float4*)&smB[kr][c4 * 4] =
          *(const float4*)(W + (size_t)(kc * 64 + kr) * 512 + col0 + c4 * 4);
    }
    __syncthreads();
#pragma unroll 4
    for (int k2 = 0; k2 < 64; ++k2) {
      float4 b = *(const float4*)&smB[k2][tc * 4];
      float a0 = smA[tr * 4 + 0][kc * 64 + k2];
      float a1 = smA[tr * 4 + 1][kc * 64 + k2];
      float a2 = smA[tr * 4 + 2][kc * 64 + k2];
      float a3 = smA[tr * 4 + 3][kc * 64 + k2];
#pragma unroll
      for (int j = 0; j < 4; ++j) {
        acc[0][j] += a0 * b[j];
        acc[1][j] += a1 * b[j];
        acc[2][j] += a2 * b[j];
        acc[3][j] += a3 * b[j];
      }
    }
  }

  float4 bb = *(const float4*)(bias + col0 + tc * 4);
  const int r0 = rb * 32 + tr * 4;
#pragma unroll
  for (int ii = 0; ii < 4; ++ii) {
    float4 o;
#pragma unroll
    for (int j = 0; j < 4; ++j) o[j] = acc[ii][j] + bb[j];
    *(float4*)(Op + (size_t)(r0 + ii) * 512 + col0 + tc * 4) = o;
  }
}

// ---------------------------------------------------------------------------
// Kernel B: fp32 flash attention, v3.
// 256 blocks x 512 threads (8 waves = 2/SIMD). Block = 32 q-rows; wave owns 4.
// Key loop: 32 tiles of 256 keys. Per tile: 8 K-chunks (256 keys x 64 d,
// LDS stride 68 -> conflict-free b128 reads) then 8 V-chunks (32 keys x 512).
// Double-buffered LDS (2 x 69,632 B); per slot: compute -> ds_write(prefetched
// regs) -> issue loads for slot+2 -> barrier. 1 barrier/slot, 16 slots/tile.
// Accumulation order identical to round-2 kernel (d ascending, keys seq).
// ---------------------------------------------------------------------------
#define FT_SLOTS 512   // 32 kt * 16 slots

__global__ __launch_bounds__(512, 2) void flash_f32(
    const float* __restrict__ Q, const float* __restrict__ K,
    const float* __restrict__ V, float* __restrict__ Out)
{
  __shared__ float buf[2][17408];   // 2 x 69,632 B
  const int t  = threadIdx.x;
  const int tx = t & 63;
  const int w  = t >> 6;
  const int r0 = blockIdx.x * 32 + w * 4;
  const float sc = 0.04419417382415922f;  // 1/sqrt(512)

  float O[4][8];
#pragma unroll
  for (int i = 0; i < 4; ++i)
#pragma unroll
    for (int n = 0; n < 8; ++n) O[i][n] = 0.f;
  float m[4], l[4];
#pragma unroll
  for (int i = 0; i < 4; ++i) { m[i] = -1e30f; l[i] = 0.f; }

  float4 pre[8];

  // slot S in [0,512): kt = S>>4, s = S&15. s<8: K chunk dc=s; else V chunk.
  auto issue_loads = [&](int S) {
    if (S >= FT_SLOTS) S = FT_SLOTS - 1;
    const int kt = S >> 4, s = S & 15;
    if (s < 8) {
      const float* base = K + (size_t)kt * 256 * 512 + s * 64;
#pragma unroll
      for (int it = 0; it < 8; ++it) {
        int idx = it * 512 + t;
        int key = idx >> 4, dq = idx & 15;
        pre[it] = *(const float4*)(base + (size_t)key * 512 + dq * 4);
      }
    } else {
      const float* base = V + (size_t)(kt * 256 + (s - 8) * 32) * 512;
#pragma unroll
      for (int it = 0; it < 8; ++it) {
        int idx = it * 512 + t;
        int key = idx >> 7, c4 = (idx & 127) * 4;
        pre[it] = *(const float4*)(base + (size_t)key * 512 + c4);
      }
    }
  };
  auto write_lds = [&](int S, float* dst) {
    if (S >= FT_SLOTS) S = FT_SLOTS - 1;
    const int s = S & 15;
    if (s < 8) {
#pragma unroll
      for (int it = 0; it < 8; ++it) {
        int idx = it * 512 + t;
        int key = idx >> 4, dq = idx & 15;
        *(float4*)&dst[key * 68 + dq * 4] = pre[it];
      }
    } else {
#pragma unroll
      for (int it = 0; it < 8; ++it) {
        int idx = it * 512 + t;
        int key = idx >> 7, c4 = (idx & 127) * 4;
        *(float4*)&dst[key * 512 + c4] = pre[it];
      }
    }
  };

  // prologue: slot 0 into buf[0]; slot 1 in flight; Q chunk 0 in flight
  issue_loads(0);
  write_lds(0, (float*)buf[0]);
  issue_loads(1);
  float qn[4];
#pragma unroll
  for (int i = 0; i < 4; ++i) qn[i] = Q[(size_t)(r0 + i) * 512 + tx];
  __syncthreads();

  float p[4][4];
  int S = 0;
#pragma unroll 1
  for (int kt = 0; kt < 32; ++kt) {
#pragma unroll
    for (int i = 0; i < 4; ++i)
#pragma unroll
      for (int j = 0; j < 4; ++j) p[i][j] = 0.f;

    // ---- QK^T: 8 chunks of 64 d ----
#pragma unroll 1
    for (int dc = 0; dc < 8; ++dc, ++S) {
      const float* bc = buf[S & 1];
      float qc[4];
#pragma unroll
      for (int i = 0; i < 4; ++i) qc[i] = qn[i];
      {  // prefetch next Q chunk (wraps to 0 at tile end; redundant, harmless)
        const int ndc = (dc + 1) & 7;
#pragma unroll
        for (int i = 0; i < 4; ++i)
          qn[i] = Q[(size_t)(r0 + i) * 512 + ndc * 64 + tx];
      }
#pragma unroll
      for (int u = 0; u < 16; ++u) {
        f32x4 kv[4];
#pragma unroll
        for (int j = 0; j < 4; ++j)
          kv[j] = *(const f32x4*)&bc[(j * 64 + tx) * 68 + u * 4];
#pragma unroll
        for (int e = 0; e < 4; ++e) {
          float qs0 = readlane_f(qc[0], u * 4 + e);
          float qs1 = readlane_f(qc[1], u * 4 + e);
          float qs2 = readlane_f(qc[2], u * 4 + e);
          float qs3 = readlane_f(qc[3], u * 4 + e);
#pragma unroll
          for (int j = 0; j < 4; ++j) {
            p[0][j] = fmaf(qs0, kv[j][e], p[0][j]);
            p[1][j] = fmaf(qs1, kv[j][e], p[1][j]);
            p[2][j] = fmaf(qs2, kv[j][e], p[2][j]);
            p[3][j] = fmaf(qs3, kv[j][e], p[3][j]);
          }
        }
      }
      write_lds(S + 1, (float*)buf[(S + 1) & 1]);
      issue_loads(S + 2);
      __syncthreads();
    }

    // ---- online softmax (identical math/order to v2) ----
#pragma unroll
    for (int i = 0; i < 4; ++i) {
      float rmax = -1e30f;
#pragma unroll
      for (int j = 0; j < 4; ++j) { p[i][j] *= sc; rmax = fmaxf(rmax, p[i][j]); }
#pragma unroll
      for (int o = 1; o < 64; o <<= 1) rmax = fmaxf(rmax, __shfl_xor(rmax, o));
      float mn = fmaxf(m[i], rmax);
      float corr = __expf(m[i] - mn);
      m[i] = mn;
      float ps = 0.f;
#pragma unroll
      for (int j = 0; j < 4; ++j) { float e = __expf(p[i][j] - mn); p[i][j] = e; ps += e; }
#pragma unroll
      for (int o = 1; o < 64; o <<= 1) ps += __shfl_xor(ps, o);
      l[i] = l[i] * corr + ps;
#pragma unroll
      for (int n = 0; n < 8; ++n) O[i][n] *= corr;
    }

    // ---- PV: 8 chunks of 32 keys ----
#pragma unroll 1
    for (int v = 0; v < 8; ++v, ++S) {
      const float* bc = buf[S & 1];
      const int j = v >> 1;
      const int base_lane = (v & 1) * 32;
#pragma unroll 8
      for (int kk = 0; kk < 32; ++kk) {
        float pv0 = readlane_f(p[0][j], base_lane + kk);
        float pv1 = readlane_f(p[1][j], base_lane + kk);
        float pv2 = readlane_f(p[2][j], base_lane + kk);
        float pv3 = readlane_f(p[3][j], base_lane + kk);
        const float* vr = &bc[kk * 512 + tx];
#pragma unroll
        for (int n = 0; n < 8; ++n) {
          float vv = vr[n * 64];
          O[0][n] = fmaf(pv0, vv, O[0][n]);
          O[1][n] = fmaf(pv1, vv, O[1][n]);
          O[2][n] = fmaf(pv2, vv, O[2][n]);
          O[3][n] = fmaf(pv3, vv, O[3][n]);
        }
      }
      write_lds(S + 1, (float*)buf[(S + 1) & 1]);
      issue_loads(S + 2);
      __syncthreads();
    }
  }

  // epilogue
#pragma unroll
  for (int i = 0; i < 4; ++i) {
    float inv = 1.0f / l[i];
#pragma unroll
    for (int n = 0; n < 8; ++n)
      Out[(size_t)(r0 + i) * 512 + n * 64 + tx] = O[i][n] * inv;
  }
}

// ---------------------------------------------------------------------------
// Kernel C: h = Out(8192x512) @ W1(512x512) + b1   (fp32 tiled)
// ---------------------------------------------------------------------------
__global__ __launch_bounds__(256) void mlp1_kernel(
    const float* __restrict__ X, const float* __restrict__ W1,
    const float* __restrict__ b1, float* __restrict__ Ho)
{
  __shared__ float smA[32][64];
  __shared__ float smB[64][128];
  const int t = threadIdx.x;
  const int cb = blockIdx.x;
  const int rb = blockIdx.y;
  const int col0 = cb * 128;
  const int tr = t >> 5, tc = t & 31;
  float acc[4][4] = {};
#pragma unroll 1
  for (int kc = 0; kc < 8; ++kc) {
    __syncthreads();
#pragma unroll
    for (int i = 0; i < 2; ++i) {
      int id = i * 256 + t;
      int r = id >> 4, c4 = id & 15;
      *(float4*)&smA[r][c4 * 4] =
          *(const float4*)(X + (size_t)(rb * 32 + r) * 512 + kc * 64 + c4 * 4);
    }
#pragma unroll
    for (int i = 0; i < 8; ++i) {
      int id = i * 256 + t;
      int kr = id >> 5, c4 = id & 31;
      *(float4*)&smB[kr][c4 * 4] =
          *(const float4*)(W1 + (size_t)(kc * 64 + kr) * 512 + col0 + c4 * 4);
    }
    __syncthreads();
#pragma unroll 4
    for (int k2 = 0; k2 < 64; ++k2) {
      float4 b = *(const float4*)&smB[k2][tc * 4];
      float a0 = smA[tr * 4 + 0][k2];
      float a1 = smA[tr * 4 + 1][k2];
      float a2 = smA[tr * 4 + 2][k2];
      float a3 = smA[tr * 4 + 3][k2];
#pragma unroll
      for (int j = 0; j < 4; ++j) {
        acc[0][j] += a0 * b[j];
        acc[1][j] += a1 * b[j];
        acc[2][j] += a2 * b[j];
        acc[3][j] += a3 * b[j];
      }
    }
  }
  const int r0 = rb * 32 + tr * 4;
  float4 bb = *(const float4*)(b1 + col0 + tc * 4);
#pragma unroll
  for (int ii = 0; ii < 4; ++ii) {
    float4 o;
#pragma unroll
    for (int j = 0; j < 4; ++j) o[j] = acc[ii][j] + bb[j];
    *(float4*)(Ho + (size_t)(r0 + ii) * 512 + col0 + tc * 4) = o;
  }
}

// ---------------------------------------------------------------------------
// Kernel D: per-row LayerNorm + ReLU + (512->2) head. One wave per row.
// ---------------------------------------------------------------------------
__global__ __launch_bounds__(256) void act_kernel(
    const float* __restrict__ H, const float* __restrict__ g1,
    const float* __restrict__ be1, const float* __restrict__ W2,
    const float* __restrict__ b2, float* __restrict__ act)
{
  const int lane = threadIdx.x & 63;
  const int w = threadIdx.x >> 6;
  const int row = blockIdx.x * 4 + w;
  const float* h = H + (size_t)row * 512;
  float x[8];
  *(float4*)&x[0] = *(const float4*)(h + lane * 8);
  *(float4*)&x[4] = *(const float4*)(h + lane * 8 + 4);
  float s = 0.f;
#pragma unroll
  for (int j = 0; j < 8; ++j) s += x[j];
#pragma unroll
  for (int o = 1; o < 64; o <<= 1) s += __shfl_xor(s, o);
  const float mu = s * (1.0f / 512.0f);
  float vs = 0.f;
#pragma unroll
  for (int j = 0; j < 8; ++j) { float d = x[j] - mu; vs += d * d; }
#pragma unroll
  for (int o = 1; o < 64; o <<= 1) vs += __shfl_xor(vs, o);
  const float rs = 1.0f / sqrtf(vs * (1.0f / 512.0f) + 1e-5f);
  float at = 0.f, ad = 0.f;
#pragma unroll
  for (int j = 0; j < 8; ++j) {
    int c = lane * 8 + j;
    float xn = (x[j] - mu) * rs * g1[c] + be1[c];
    xn = fmaxf(xn, 0.0f);
    at += xn * W2[2 * c];
    ad += xn * W2[2 * c + 1];
  }
#pragma unroll
  for (int o = 1; o < 64; o <<= 1) { at += __shfl_xor(at, o); ad += __shfl_xor(ad, o); }
  if (lane == 0) {
    act[row * 2 + 0] = at + b2[0];
    act[row * 2 + 1] = ad + b2[1];
  }
}

// ---------------------------------------------------------------------------
// Kernel E: 100-step bicycle model, jax op order exact (incl. per-step
// atan2(sin,cos) wrap). f_load = 0 (C_A=C_R=0).
// ---------------------------------------------------------------------------
__global__ __launch_bounds__(256) void physics_kernel(
    const float* __restrict__ obs, const float* __restrict__ act,
    float* __restrict__ out)
{
  const int row = blockIdx.x * 256 + threadIdx.x;
  const float* o = obs + (size_t)row * 128;
  float xx = o[0] * 10.0f;
  float yy = o[1] * 10.0f;
  float vx = o[2] * 10.0f;
  float vy = o[3] * 10.0f;
  float yw = o[4] * 10.0f;
  float vv = sqrtf(vx * vx + vy * vy);
  const float th = act[row * 2 + 0];
  const float de = act[row * 2 + 1];
  const float dt_s = 0.001f;
  const float inv_wb = (float)(1.0 / 2.96);
  const float td = tanf(de);
#pragma unroll 1
  for (int i = 0; i < 100; ++i) {
    vv = vv + th * dt_s;
    float s1 = sinf(yw), c1 = cosf(yw);
    xx = xx + vv * c1 * dt_s;
    yy = yy + vv * s1 * dt_s;
    yw = yw + ((vv * td) * inv_wb) * dt_s;
    yw = atan2f(sinf(yw), cosf(yw));
  }
  float cf = cosf(yw), sf = sinf(yw);
  out[row * 5 + 0] = xx * 0.1f;
  out[row * 5 + 1] = yy * 0.1f;
  out[row * 5 + 2] = vv * cf * 0.1f;
  out[row * 5 + 3] = vv * sf * 0.1f;
  out[row * 5 + 4] = yw * 0.1f;
}

// ---------------------------------------------------------------------------
extern "C" void kernel_launch(void* const* d_in, const int* in_sizes, int n_in,
                              void* d_out, int out_size, void* d_ws, size_t ws_size,
                              hipStream_t stream) {
  const float* obs = (const float*)d_in[0];
  const float* Wq  = (const float*)d_in[1];
  const float* bq  = (const float*)d_in[2];
  const float* Wk  = (const float*)d_in[3];
  const float* bk  = (const float*)d_in[4];
  const float* Wv  = (const float*)d_in[5];
  const float* bv  = (const float*)d_in[6];
  const float* W1  = (const float*)d_in[7];
  const float* b1  = (const float*)d_in[8];
  const float* g1  = (const float*)d_in[9];
  const float* be1 = (const float*)d_in[10];
  const float* W2  = (const float*)d_in[11];
  const float* b2  = (const float*)d_in[12];

  char* ws = (char*)d_ws;
  float* Qf  = (float*)(ws);                         // [0,16M)
  float* Kf  = (float*)(ws + (size_t)(16 << 20));    // [16M,32M)
  float* Vf  = (float*)(ws + (size_t)(32 << 20));    // [32M,48M)
  float* Aout= (float*)(ws + (size_t)(48 << 20));    // [48M,64M)
  float* Ho  = (float*)(ws);                         // reuse [0,16M)
  float* Act = (float*)(ws + (size_t)(16 << 20));    // reuse [16M,+64K)
  float* out = (float*)d_out;

  qkv_f32<<<dim3(12, 256), 256, 0, stream>>>(obs, Wq, bq, Wk, bk, Wv, bv, Qf, Kf, Vf);
  flash_f32<<<dim3(256), 512, 0, stream>>>(Qf, Kf, Vf, Aout);
  mlp1_kernel<<<dim3(4, 256), 256, 0, stream>>>(Aout, W1, b1, Ho);
  act_kernel<<<dim3(2048), 256, 0, stream>>>(Ho, g1, be1, W2, b2, Act);
  physics_kernel<<<dim3(32), 256, 0, stream>>>(obs, Act, out);
}

// Round 5
// 8561.491 us; speedup vs baseline: 1.0080x; 1.0080x over previous
//
#include <hip/hip_runtime.h>
#include <stdint.h>

// All-fp32 pipeline (bf16 fails: LN amplifies attention error x55, tan(delta)
// physics is chaotic near |delta|=pi/2 -> need fp32-accurate delta).

__device__ __forceinline__ float readlane_f(float v, int lane) {
  return __uint_as_float(__builtin_amdgcn_readlane(__float_as_uint(v), lane));
}
typedef __attribute__((ext_vector_type(4))) float f32x4;

// ---------------------------------------------------------------------------
// Kernel A: fused QKV projection (fp32). obs(8192x128) @ {Wq,Wk,Wv}(128x512)+b
// ---------------------------------------------------------------------------
__global__ __launch_bounds__(256) void qkv_f32(
    const float* __restrict__ obs,
    const float* __restrict__ Wq, const float* __restrict__ bq,
    const float* __restrict__ Wk, const float* __restrict__ bk,
    const float* __restrict__ Wv, const float* __restrict__ bv,
    float* __restrict__ Qf, float* __restrict__ Kf, float* __restrict__ Vf)
{
  __shared__ float smA[32][128];
  __shared__ float smB[64][128];
  const int t  = threadIdx.x;
  const int cb = blockIdx.x;
  const int rb = blockIdx.y;
  const float* W; const float* bias; float* Op;
  if (cb < 4)      { W = Wq; bias = bq; Op = Qf; }
  else if (cb < 8) { W = Wk; bias = bk; Op = Kf; }
  else             { W = Wv; bias = bv; Op = Vf; }
  const int col0 = (cb & 3) * 128;

  {
    const float4* src = (const float4*)(obs + (size_t)rb * (32 * 128));
    float4* dst = (float4*)&smA[0][0];
#pragma unroll
    for (int i = 0; i < 4; ++i) dst[i * 256 + t] = src[i * 256 + t];
  }

  const int tr = t >> 5, tc = t & 31;
  float acc[4][4] = {};
#pragma unroll 1
  for (int kc = 0; kc < 2; ++kc) {
    __syncthreads();
#pragma unroll
    for (int i = 0; i < 8; ++i) {
      int id = i * 256 + t;
      int kr = id >> 5, c4 = id & 31;
      *(float4*)&smB[kr][c4 * 4] =
          *(const float4*)(W + (size_t)(kc * 64 + kr) * 512 + col0 + c4 * 4);
    }
    __syncthreads();
#pragma unroll 4
    for (int k2 = 0; k2 < 64; ++k2) {
      float4 b = *(const float4*)&smB[k2][tc * 4];
      float a0 = smA[tr * 4 + 0][kc * 64 + k2];
      float a1 = smA[tr * 4 + 1][kc * 64 + k2];
      float a2 = smA[tr * 4 + 2][kc * 64 + k2];
      float a3 = smA[tr * 4 + 3][kc * 64 + k2];
#pragma unroll
      for (int j = 0; j < 4; ++j) {
        acc[0][j] += a0 * b[j];
        acc[1][j] += a1 * b[j];
        acc[2][j] += a2 * b[j];
        acc[3][j] += a3 * b[j];
      }
    }
  }

  float4 bb = *(const float4*)(bias + col0 + tc * 4);
  const int r0 = rb * 32 + tr * 4;
#pragma unroll
  for (int ii = 0; ii < 4; ++ii) {
    float4 o;
#pragma unroll
    for (int j = 0; j < 4; ++j) o[j] = acc[ii][j] + bb[j];
    *(float4*)(Op + (size_t)(r0 + ii) * 512 + col0 + tc * 4) = o;
  }
}

// ---------------------------------------------------------------------------
// Kernel B: fp32 flash attention, v4.
// 256 blocks x 512 threads (8 waves = 2/SIMD, 1 block/CU, LDS-limited).
// Block = 32 q-rows; wave owns 4. 32 key-tiles of 256 keys; per tile:
// 8 K-chunks (256 keys x 64 d, LDS stride 68: measured 0 bank conflicts)
// then 8 V-chunks (32 keys x 512 d). Double-buffered LDS (2 x 69,632 B);
// per slot: compute -> ds_write(prefetched regs) -> issue loads slot+2 ->
// barrier.
// v4 fixes: __launch_bounds__(512,1) (the (512,2) cap at 128 VGPRs spilled
// pre[8] -> 29 GB/dispatch of scratch HBM traffic = whole runtime);
// PV reads V as 2x ds_read_b128 (cols n2*256+tx*4+e) instead of 8x b32.
// Per-element accumulation order identical to rounds 2-4 (k ascending).
// ---------------------------------------------------------------------------
#define FT_SLOTS 512   // 32 kt * 16 slots

__global__ __launch_bounds__(512, 1) void flash_f32(
    const float* __restrict__ Q, const float* __restrict__ K,
    const float* __restrict__ V, float* __restrict__ Out)
{
  __shared__ float buf[2][17408];   // 2 x 69,632 B
  const int t  = threadIdx.x;
  const int tx = t & 63;
  const int w  = t >> 6;
  const int r0 = blockIdx.x * 32 + w * 4;
  const float sc = 0.04419417382415922f;  // 1/sqrt(512)

  float O[4][8];
#pragma unroll
  for (int i = 0; i < 4; ++i)
#pragma unroll
    for (int n = 0; n < 8; ++n) O[i][n] = 0.f;
  float m[4], l[4];
#pragma unroll
  for (int i = 0; i < 4; ++i) { m[i] = -1e30f; l[i] = 0.f; }

  float4 pre[8];

  // slot S in [0,512): kt = S>>4, s = S&15. s<8: K chunk dc=s; else V chunk.
  auto issue_loads = [&](int S) {
    if (S >= FT_SLOTS) S = FT_SLOTS - 1;
    const int kt = S >> 4, s = S & 15;
    if (s < 8) {
      const float* base = K + (size_t)kt * 256 * 512 + s * 64;
#pragma unroll
      for (int it = 0; it < 8; ++it) {
        int idx = it * 512 + t;
        int key = idx >> 4, dq = idx & 15;
        pre[it] = *(const float4*)(base + (size_t)key * 512 + dq * 4);
      }
    } else {
      const float* base = V + (size_t)(kt * 256 + (s - 8) * 32) * 512;
#pragma unroll
      for (int it = 0; it < 8; ++it) {
        int idx = it * 512 + t;
        int key = idx >> 7, c4 = (idx & 127) * 4;
        pre[it] = *(const float4*)(base + (size_t)key * 512 + c4);
      }
    }
  };
  auto write_lds = [&](int S, float* dst) {
    if (S >= FT_SLOTS) S = FT_SLOTS - 1;
    const int s = S & 15;
    if (s < 8) {
#pragma unroll
      for (int it = 0; it < 8; ++it) {
        int idx = it * 512 + t;
        int key = idx >> 4, dq = idx & 15;
        *(float4*)&dst[key * 68 + dq * 4] = pre[it];
      }
    } else {
#pragma unroll
      for (int it = 0; it < 8; ++it) {
        int idx = it * 512 + t;
        int key = idx >> 7, c4 = (idx & 127) * 4;
        *(float4*)&dst[key * 512 + c4] = pre[it];
      }
    }
  };

  // prologue: slot 0 into buf[0]; slot 1 in flight; Q chunk 0 in flight
  issue_loads(0);
  write_lds(0, (float*)buf[0]);
  issue_loads(1);
  float qn[4];
#pragma unroll
  for (int i = 0; i < 4; ++i) qn[i] = Q[(size_t)(r0 + i) * 512 + tx];
  __syncthreads();

  float p[4][4];
  int S = 0;
#pragma unroll 1
  for (int kt = 0; kt < 32; ++kt) {
#pragma unroll
    for (int i = 0; i < 4; ++i)
#pragma unroll
      for (int j = 0; j < 4; ++j) p[i][j] = 0.f;

    // ---- QK^T: 8 chunks of 64 d ----
#pragma unroll 1
    for (int dc = 0; dc < 8; ++dc, ++S) {
      const float* bc = buf[S & 1];
      float qc[4];
#pragma unroll
      for (int i = 0; i < 4; ++i) qc[i] = qn[i];
      {  // prefetch next Q chunk (wraps to 0 at tile end; redundant, harmless)
        const int ndc = (dc + 1) & 7;
#pragma unroll
        for (int i = 0; i < 4; ++i)
          qn[i] = Q[(size_t)(r0 + i) * 512 + ndc * 64 + tx];
      }
#pragma unroll
      for (int u = 0; u < 16; ++u) {
        f32x4 kv[4];
#pragma unroll
        for (int j = 0; j < 4; ++j)
          kv[j] = *(const f32x4*)&bc[(j * 64 + tx) * 68 + u * 4];
#pragma unroll
        for (int e = 0; e < 4; ++e) {
          float qs0 = readlane_f(qc[0], u * 4 + e);
          float qs1 = readlane_f(qc[1], u * 4 + e);
          float qs2 = readlane_f(qc[2], u * 4 + e);
          float qs3 = readlane_f(qc[3], u * 4 + e);
#pragma unroll
          for (int j = 0; j < 4; ++j) {
            p[0][j] = fmaf(qs0, kv[j][e], p[0][j]);
            p[1][j] = fmaf(qs1, kv[j][e], p[1][j]);
            p[2][j] = fmaf(qs2, kv[j][e], p[2][j]);
            p[3][j] = fmaf(qs3, kv[j][e], p[3][j]);
          }
        }
      }
      write_lds(S + 1, (float*)buf[(S + 1) & 1]);
      issue_loads(S + 2);
      __syncthreads();
    }

    // ---- online softmax (identical math/order to v2) ----
#pragma unroll
    for (int i = 0; i < 4; ++i) {
      float rmax = -1e30f;
#pragma unroll
      for (int j = 0; j < 4; ++j) { p[i][j] *= sc; rmax = fmaxf(rmax, p[i][j]); }
#pragma unroll
      for (int o = 1; o < 64; o <<= 1) rmax = fmaxf(rmax, __shfl_xor(rmax, o));
      float mn = fmaxf(m[i], rmax);
      float corr = __expf(m[i] - mn);
      m[i] = mn;
      float ps = 0.f;
#pragma unroll
      for (int j = 0; j < 4; ++j) { float e = __expf(p[i][j] - mn); p[i][j] = e; ps += e; }
#pragma unroll
      for (int o = 1; o < 64; o <<= 1) ps += __shfl_xor(ps, o);
      l[i] = l[i] * corr + ps;
#pragma unroll
      for (int n = 0; n < 8; ++n) O[i][n] *= corr;
    }

    // ---- PV: 8 chunks of 32 keys; V read as 2x b128 per key ----
    // O[i][n] holds column n2*256 + tx*4 + e  (n = n2*4+e)
#pragma unroll 1
    for (int v = 0; v < 8; ++v, ++S) {
      const float* bc = buf[S & 1];
      const int j = v >> 1;
      const int base_lane = (v & 1) * 32;
#pragma unroll 8
      for (int kk = 0; kk < 32; ++kk) {
        float pv0 = readlane_f(p[0][j], base_lane + kk);
        float pv1 = readlane_f(p[1][j], base_lane + kk);
        float pv2 = readlane_f(p[2][j], base_lane + kk);
        float pv3 = readlane_f(p[3][j], base_lane + kk);
        f32x4 va = *(const f32x4*)&bc[kk * 512 + tx * 4];
        f32x4 vb = *(const f32x4*)&bc[kk * 512 + 256 + tx * 4];
#pragma unroll
        for (int e = 0; e < 4; ++e) {
          O[0][e] = fmaf(pv0, va[e], O[0][e]);
          O[1][e] = fmaf(pv1, va[e], O[1][e]);
          O[2][e] = fmaf(pv2, va[e], O[2][e]);
          O[3][e] = fmaf(pv3, va[e], O[3][e]);
          O[0][4 + e] = fmaf(pv0, vb[e], O[0][4 + e]);
          O[1][4 + e] = fmaf(pv1, vb[e], O[1][4 + e]);
          O[2][4 + e] = fmaf(pv2, vb[e], O[2][4 + e]);
          O[3][4 + e] = fmaf(pv3, vb[e], O[3][4 + e]);
        }
      }
      write_lds(S + 1, (float*)buf[(S + 1) & 1]);
      issue_loads(S + 2);
      __syncthreads();
    }
  }

  // epilogue (column mapping n2*256 + tx*4 + e)
#pragma unroll
  for (int i = 0; i < 4; ++i) {
    float inv = 1.0f / l[i];
    float4 oa, ob;
#pragma unroll
    for (int e = 0; e < 4; ++e) { oa[e] = O[i][e] * inv; ob[e] = O[i][4 + e] * inv; }
    *(float4*)(Out + (size_t)(r0 + i) * 512 + tx * 4) = oa;
    *(float4*)(Out + (size_t)(r0 + i) * 512 + 256 + tx * 4) = ob;
  }
}

// ---------------------------------------------------------------------------
// Kernel C: h = Out(8192x512) @ W1(512x512) + b1   (fp32 tiled)
// ---------------------------------------------------------------------------
__global__ __launch_bounds__(256) void mlp1_kernel(
    const float* __restrict__ X, const float* __restrict__ W1,
    const float* __restrict__ b1, float* __restrict__ Ho)
{
  __shared__ float smA[32][64];
  __shared__ float smB[64][128];
  const int t = threadIdx.x;
  const int cb = blockIdx.x;
  const int rb = blockIdx.y;
  const int col0 = cb * 128;
  const int tr = t >> 5, tc = t & 31;
  float acc[4][4] = {};
#pragma unroll 1
  for (int kc = 0; kc < 8; ++kc) {
    __syncthreads();
#pragma unroll
    for (int i = 0; i < 2; ++i) {
      int id = i * 256 + t;
      int r = id >> 4, c4 = id & 15;
      *(float4*)&smA[r][c4 * 4] =
          *(const float4*)(X + (size_t)(rb * 32 + r) * 512 + kc * 64 + c4 * 4);
    }
#pragma unroll
    for (int i = 0; i < 8; ++i) {
      int id = i * 256 + t;
      int kr = id >> 5, c4 = id & 31;
      *(float4*)&smB[kr][c4 * 4] =
          *(const float4*)(W1 + (size_t)(kc * 64 + kr) * 512 + col0 + c4 * 4);
    }
    __syncthreads();
#pragma unroll 4
    for (int k2 = 0; k2 < 64; ++k2) {
      float4 b = *(const float4*)&smB[k2][tc * 4];
      float a0 = smA[tr * 4 + 0][k2];
      float a1 = smA[tr * 4 + 1][k2];
      float a2 = smA[tr * 4 + 2][k2];
      float a3 = smA[tr * 4 + 3][k2];
#pragma unroll
      for (int j = 0; j < 4; ++j) {
        acc[0][j] += a0 * b[j];
        acc[1][j] += a1 * b[j];
        acc[2][j] += a2 * b[j];
        acc[3][j] += a3 * b[j];
      }
    }
  }
  const int r0 = rb * 32 + tr * 4;
  float4 bb = *(const float4*)(b1 + col0 + tc * 4);
#pragma unroll
  for (int ii = 0; ii < 4; ++ii) {
    float4 o;
#pragma unroll
    for (int j = 0; j < 4; ++j) o[j] = acc[ii][j] + bb[j];
    *(float4*)(Ho + (size_t)(r0 + ii) * 512 + col0 + tc * 4) = o;
  }
}

// ---------------------------------------------------------------------------
// Kernel D: per-row LayerNorm + ReLU + (512->2) head. One wave per row.
// ---------------------------------------------------------------------------
__global__ __launch_bounds__(256) void act_kernel(
    const float* __restrict__ H, const float* __restrict__ g1,
    const float* __restrict__ be1, const float* __restrict__ W2,
    const float* __restrict__ b2, float* __restrict__ act)
{
  const int lane = threadIdx.x & 63;
  const int w = threadIdx.x >> 6;
  const int row = blockIdx.x * 4 + w;
  const float* h = H + (size_t)row * 512;
  float x[8];
  *(float4*)&x[0] = *(const float4*)(h + lane * 8);
  *(float4*)&x[4] = *(const float4*)(h + lane * 8 + 4);
  float s = 0.f;
#pragma unroll
  for (int j = 0; j < 8; ++j) s += x[j];
#pragma unroll
  for (int o = 1; o < 64; o <<= 1) s += __shfl_xor(s, o);
  const float mu = s * (1.0f / 512.0f);
  float vs = 0.f;
#pragma unroll
  for (int j = 0; j < 8; ++j) { float d = x[j] - mu; vs += d * d; }
#pragma unroll
  for (int o = 1; o < 64; o <<= 1) vs += __shfl_xor(vs, o);
  const float rs = 1.0f / sqrtf(vs * (1.0f / 512.0f) + 1e-5f);
  float at = 0.f, ad = 0.f;
#pragma unroll
  for (int j = 0; j < 8; ++j) {
    int c = lane * 8 + j;
    float xn = (x[j] - mu) * rs * g1[c] + be1[c];
    xn = fmaxf(xn, 0.0f);
    at += xn * W2[2 * c];
    ad += xn * W2[2 * c + 1];
  }
#pragma unroll
  for (int o = 1; o < 64; o <<= 1) { at += __shfl_xor(at, o); ad += __shfl_xor(ad, o); }
  if (lane == 0) {
    act[row * 2 + 0] = at + b2[0];
    act[row * 2 + 1] = ad + b2[1];
  }
}

// ---------------------------------------------------------------------------
// Kernel E: 100-step bicycle model, jax op order exact (incl. per-step
// atan2(sin,cos) wrap). f_load = 0 (C_A=C_R=0).
// ---------------------------------------------------------------------------
__global__ __launch_bounds__(256) void physics_kernel(
    const float* __restrict__ obs, const float* __restrict__ act,
    float* __restrict__ out)
{
  const int row = blockIdx.x * 256 + threadIdx.x;
  const float* o = obs + (size_t)row * 128;
  float xx = o[0] * 10.0f;
  float yy = o[1] * 10.0f;
  float vx = o[2] * 10.0f;
  float vy = o[3] * 10.0f;
  float yw = o[4] * 10.0f;
  float vv = sqrtf(vx * vx + vy * vy);
  const float th = act[row * 2 + 0];
  const float de = act[row * 2 + 1];
  const float dt_s = 0.001f;
  const float inv_wb = (float)(1.0 / 2.96);
  const float td = tanf(de);
#pragma unroll 1
  for (int i = 0; i < 100; ++i) {
    vv = vv + th * dt_s;
    float s1 = sinf(yw), c1 = cosf(yw);
    xx = xx + vv * c1 * dt_s;
    yy = yy + vv * s1 * dt_s;
    yw = yw + ((vv * td) * inv_wb) * dt_s;
    yw = atan2f(sinf(yw), cosf(yw));
  }
  float cf = cosf(yw), sf = sinf(yw);
  out[row * 5 + 0] = xx * 0.1f;
  out[row * 5 + 1] = yy * 0.1f;
  out[row * 5 + 2] = vv * cf * 0.1f;
  out[row * 5 + 3] = vv * sf * 0.1f;
  out[row * 5 + 4] = yw * 0.1f;
}

// ---------------------------------------------------------------------------
extern "C" void kernel_launch(void* const* d_in, const int* in_sizes, int n_in,
                              void* d_out, int out_size, void* d_ws, size_t ws_size,
                              hipStream_t stream) {
  const float* obs = (const float*)d_in[0];
  const float* Wq  = (const float*)d_in[1];
  const float* bq  = (const float*)d_in[2];
  const float* Wk  = (const float*)d_in[3];
  const float* bk  = (const float*)d_in[4];
  const float* Wv  = (const float*)d_in[5];
  const float* bv  = (const float*)d_in[6];
  const float* W1  = (const float*)d_in[7];
  const float* b1  = (const float*)d_in[8];
  const float* g1  = (const float*)d_in[9];
  const float* be1 = (const float*)d_in[10];
  const float* W2  = (const float*)d_in[11];
  const float* b2  = (const float*)d_in[12];

  char* ws = (char*)d_ws;
  float* Qf  = (float*)(ws);                         // [0,16M)
  float* Kf  = (float*)(ws + (size_t)(16 << 20));    // [16M,32M)
  float* Vf  = (float*)(ws + (size_t)(32 << 20));    // [32M,48M)
  float* Aout= (float*)(ws + (size_t)(48 << 20));    // [48M,64M)
  float* Ho  = (float*)(ws);                         // reuse [0,16M)
  float* Act = (float*)(ws + (size_t)(16 << 20));    // reuse [16M,+64K)
  float* out = (float*)d_out;

  qkv_f32<<<dim3(12, 256), 256, 0, stream>>>(obs, Wq, bq, Wk, bk, Wv, bv, Qf, Kf, Vf);
  flash_f32<<<dim3(256), 512, 0, stream>>>(Qf, Kf, Vf, Aout);
  mlp1_kernel<<<dim3(4, 256), 256, 0, stream>>>(Aout, W1, b1, Ho);
  act_kernel<<<dim3(2048), 256, 0, stream>>>(Ho, g1, be1, W2, b2, Act);
  physics_kernel<<<dim3(32), 256, 0, stream>>>(obs, Act, out);
}

// Round 6
// 2481.724 us; speedup vs baseline: 3.4774x; 3.4498x over previous
//
#include <hip/hip_runtime.h>
#include <stdint.h>

// All-fp32 pipeline (bf16/split-bf16 fail: LN amplifies attention error x55,
// tan(delta) physics is chaotic near |delta|=pi/2 -> need fp32 delta).

typedef __attribute__((ext_vector_type(4))) float f32x4;

__device__ __forceinline__ float readlane_f(float v, int lane) {
  return __uint_as_float(__builtin_amdgcn_readlane(__float_as_uint(v), lane));
}

typedef __attribute__((address_space(3))) uint32_t lds_u32;
typedef const __attribute__((address_space(1))) uint32_t glb_u32;
__device__ __forceinline__ void gload16(const void* g, void* l) {
  // global -> LDS direct copy; LDS dest = l + lane*16 (wave-uniform l).
  __builtin_amdgcn_global_load_lds((glb_u32*)g, (lds_u32*)l, 16, 0, 0);
}

// ---------------------------------------------------------------------------
// Kernel A: fused QKV projection (fp32). obs(8192x128) @ {Wq,Wk,Wv}(128x512)+b
// ---------------------------------------------------------------------------
__global__ __launch_bounds__(256) void qkv_f32(
    const float* __restrict__ obs,
    const float* __restrict__ Wq, const float* __restrict__ bq,
    const float* __restrict__ Wk, const float* __restrict__ bk,
    const float* __restrict__ Wv, const float* __restrict__ bv,
    float* __restrict__ Qf, float* __restrict__ Kf, float* __restrict__ Vf)
{
  __shared__ float smA[32][128];
  __shared__ float smB[64][128];
  const int t  = threadIdx.x;
  const int cb = blockIdx.x;
  const int rb = blockIdx.y;
  const float* W; const float* bias; float* Op;
  if (cb < 4)      { W = Wq; bias = bq; Op = Qf; }
  else if (cb < 8) { W = Wk; bias = bk; Op = Kf; }
  else             { W = Wv; bias = bv; Op = Vf; }
  const int col0 = (cb & 3) * 128;

  {
    const float4* src = (const float4*)(obs + (size_t)rb * (32 * 128));
    float4* dst = (float4*)&smA[0][0];
#pragma unroll
    for (int i = 0; i < 4; ++i) dst[i * 256 + t] = src[i * 256 + t];
  }

  const int tr = t >> 5, tc = t & 31;
  float acc[4][4] = {};
#pragma unroll 1
  for (int kc = 0; kc < 2; ++kc) {
    __syncthreads();
#pragma unroll
    for (int i = 0; i < 8; ++i) {
      int id = i * 256 + t;
      int kr = id >> 5, c4 = id & 31;
      *(float4*)&smB[kr][c4 * 4] =
          *(const float4*)(W + (size_t)(kc * 64 + kr) * 512 + col0 + c4 * 4);
    }
    __syncthreads();
#pragma unroll 4
    for (int k2 = 0; k2 < 64; ++k2) {
      float4 b = *(const float4*)&smB[k2][tc * 4];
      float a0 = smA[tr * 4 + 0][kc * 64 + k2];
      float a1 = smA[tr * 4 + 1][kc * 64 + k2];
      float a2 = smA[tr * 4 + 2][kc * 64 + k2];
      float a3 = smA[tr * 4 + 3][kc * 64 + k2];
#pragma unroll
      for (int j = 0; j < 4; ++j) {
        acc[0][j] += a0 * b[j];
        acc[1][j] += a1 * b[j];
        acc[2][j] += a2 * b[j];
        acc[3][j] += a3 * b[j];
      }
    }
  }

  float4 bb = *(const float4*)(bias + col0 + tc * 4);
  const int r0 = rb * 32 + tr * 4;
#pragma unroll
  for (int ii = 0; ii < 4; ++ii) {
    float4 o;
#pragma unroll
    for (int j = 0; j < 4; ++j) o[j] = acc[ii][j] + bb[j];
    *(float4*)(Op + (size_t)(r0 + ii) * 512 + col0 + tc * 4) = o;
  }
}

// ---------------------------------------------------------------------------
// Kernel B: fp32 flash attention, v6 (global_load_lds + counted vmcnt).
// 256 blocks x 512 threads (8 waves). Block = 32 q-rows; wave owns 4.
// Slots: per key-tile (256 keys): 16 K-slots (256 keys x 32 d, 32KB,
// XOR-swizzled source: cbyte ^= ((key&7)<<4)) then 16 V-slots (16 keys x
// 512 d, linear). 3 x 32KB LDS slot buffers, depth-2 prefetch, one raw
// s_barrier + s_waitcnt vmcnt(4) per slot (never drained to 0 mid-loop).
// Q tile (32x512, 64KB) staged once in LDS; per-slot 4x ds_read_b32 feed
// v_readlane broadcasts. No register staging, no runtime-indexed reg arrays
// (v4/v5 spilled 18GB/dispatch of scratch: pre[8] + p[i][runtime j]).
// FMA order per accumulator identical to rounds 2-5 -> absmax unchanged.
// ---------------------------------------------------------------------------
#define FLASH_NSLOTS 1024

__global__ __launch_bounds__(512, 2) void flash_f32(
    const float* __restrict__ Q, const float* __restrict__ K,
    const float* __restrict__ V, float* __restrict__ Out)
{
  __shared__ __align__(16) char lds[163840];   // 64KB Qlds + 3 x 32KB bufs
  float* Qlds = (float*)lds;
  char*  bufb = lds + 65536;
  const int t  = threadIdx.x;
  const int tx = t & 63;
  const int w  = t >> 6;
  const int qrow0 = blockIdx.x * 32;
  const int r0 = qrow0 + w * 4;
  const float sc = 0.04419417382415922f;  // 1/sqrt(512)

  // ---- stage slot S into buffer bidx: 4 global_load_lds_dwordx4/thread ----
  auto stage = [&](int S, int bidx) {
    if (S >= FLASH_NSLOTS) S = FLASH_NSLOTS - 1;  // clamp keeps vmcnt exact
    char* lb = bufb + (bidx << 15);
    const int kt = S >> 5, sub = S & 31;
    if (sub < 16) {
      // K-slot: keys kt*256..+255, d-range [sub*32, +32), source pre-swizzled
      const int key_in = tx >> 3;                   // 0..7
      const int csw = ((tx & 7) ^ key_in) << 4;     // swizzled 16B slot
      const char* gb = (const char*)K + ((size_t)kt * 256) * 2048
                     + (size_t)sub * 128 + csw;
#pragma unroll
      for (int c = 0; c < 4; ++c)
        gload16(gb + (size_t)((c * 8 + w) * 8 + key_in) * 2048,
                lb + ((c * 8 + w) << 10));
    } else {
      // V-slot: keys kt*256 + (sub-16)*16 .. +15, linear 32KB copy
      const char* gb = (const char*)V
                     + ((size_t)(kt * 256 + (sub - 16) * 16)) * 2048 + tx * 16;
#pragma unroll
      for (int c = 0; c < 4; ++c)
        gload16(gb + ((c * 8 + w) << 10), lb + ((c * 8 + w) << 10));
    }
  };

  // ---- prologue: Q tile + slots 0,1 ----
  {
    const char* gq = (const char*)Q + (size_t)qrow0 * 2048 + tx * 16;
#pragma unroll
    for (int c = 0; c < 8; ++c)
      gload16(gq + ((c * 8 + w) << 10), lds + ((c * 8 + w) << 10));
  }
  stage(0, 0);
  stage(1, 1);
  asm volatile("s_waitcnt vmcnt(4)" ::: "memory");  // Q + slot0 landed
  __builtin_amdgcn_s_barrier();

  float O[4][8];
#pragma unroll
  for (int i = 0; i < 4; ++i)
#pragma unroll
    for (int n = 0; n < 8; ++n) O[i][n] = 0.f;
  float m[4], l[4];
#pragma unroll
  for (int i = 0; i < 4; ++i) { m[i] = -1e30f; l[i] = 0.f; }

  int S = 0, bc = 0, bi = 2;
  const int qbase = (w * 4) * 512 + (tx & 31);
  const int kswz = (tx & 7) << 4;

#pragma unroll 1
  for (int kt = 0; kt < 32; ++kt) {
    float p[4][4];
#pragma unroll
    for (int i = 0; i < 4; ++i)
#pragma unroll
      for (int j = 0; j < 4; ++j) p[i][j] = 0.f;

    // ---- QK^T: 16 K-slots of 32 d ----
#pragma unroll 1
    for (int s = 0; s < 16; ++s) {
      stage(S + 2, bi);
      const char* kb = bufb + (bc << 15);
      float qs[4];
#pragma unroll
      for (int i = 0; i < 4; ++i) qs[i] = Qlds[qbase + i * 512 + s * 32];
#pragma unroll
      for (int u8 = 0; u8 < 8; ++u8) {
        f32x4 kv[4];
#pragma unroll
        for (int j = 0; j < 4; ++j)
          kv[j] = *(const f32x4*)(kb + ((j * 64 + tx) << 7) + ((u8 * 16) ^ kswz));
#pragma unroll
        for (int e = 0; e < 4; ++e) {
          float q0 = readlane_f(qs[0], u8 * 4 + e);
          float q1 = readlane_f(qs[1], u8 * 4 + e);
          float q2 = readlane_f(qs[2], u8 * 4 + e);
          float q3 = readlane_f(qs[3], u8 * 4 + e);
#pragma unroll
          for (int j = 0; j < 4; ++j) {
            p[0][j] = fmaf(q0, kv[j][e], p[0][j]);
            p[1][j] = fmaf(q1, kv[j][e], p[1][j]);
            p[2][j] = fmaf(q2, kv[j][e], p[2][j]);
            p[3][j] = fmaf(q3, kv[j][e], p[3][j]);
          }
        }
      }
      asm volatile("s_waitcnt vmcnt(4)" ::: "memory");
      __builtin_amdgcn_s_barrier();
      ++S; bc = (bc == 2) ? 0 : bc + 1; bi = (bi == 2) ? 0 : bi + 1;
    }

    // ---- online softmax (identical math/order to rounds 2-5) ----
#pragma unroll
    for (int i = 0; i < 4; ++i) {
      float rmax = -1e30f;
#pragma unroll
      for (int j = 0; j < 4; ++j) { p[i][j] *= sc; rmax = fmaxf(rmax, p[i][j]); }
#pragma unroll
      for (int o = 1; o < 64; o <<= 1) rmax = fmaxf(rmax, __shfl_xor(rmax, o));
      float mn = fmaxf(m[i], rmax);
      float corr = __expf(m[i] - mn);
      m[i] = mn;
      float ps = 0.f;
#pragma unroll
      for (int j = 0; j < 4; ++j) { float e = __expf(p[i][j] - mn); p[i][j] = e; ps += e; }
#pragma unroll
      for (int o = 1; o < 64; o <<= 1) ps += __shfl_xor(ps, o);
      l[i] = l[i] * corr + ps;
#pragma unroll
      for (int n = 0; n < 8; ++n) O[i][n] *= corr;
    }

    // ---- PV: 16 V-slots of 16 keys; j static (outer unrolled) ----
#pragma unroll
    for (int j = 0; j < 4; ++j) {
      float pj0 = p[0][j], pj1 = p[1][j], pj2 = p[2][j], pj3 = p[3][j];
#pragma unroll 1
      for (int v2 = 0; v2 < 4; ++v2) {
        stage(S + 2, bi);
        const char* vbuf = bufb + (bc << 15) + (tx << 4);
        const int bl = v2 * 16;
#pragma unroll
        for (int kk = 0; kk < 16; ++kk) {
          float pv0 = readlane_f(pj0, bl + kk);
          float pv1 = readlane_f(pj1, bl + kk);
          float pv2 = readlane_f(pj2, bl + kk);
          float pv3 = readlane_f(pj3, bl + kk);
          f32x4 va = *(const f32x4*)(vbuf + (kk << 11));
          f32x4 vb = *(const f32x4*)(vbuf + (kk << 11) + 1024);
#pragma unroll
          for (int e = 0; e < 4; ++e) {
            O[0][e] = fmaf(pv0, va[e], O[0][e]);
            O[1][e] = fmaf(pv1, va[e], O[1][e]);
            O[2][e] = fmaf(pv2, va[e], O[2][e]);
            O[3][e] = fmaf(pv3, va[e], O[3][e]);
            O[0][4 + e] = fmaf(pv0, vb[e], O[0][4 + e]);
            O[1][4 + e] = fmaf(pv1, vb[e], O[1][4 + e]);
            O[2][4 + e] = fmaf(pv2, vb[e], O[2][4 + e]);
            O[3][4 + e] = fmaf(pv3, vb[e], O[3][4 + e]);
          }
        }
        asm volatile("s_waitcnt vmcnt(4)" ::: "memory");
        __builtin_amdgcn_s_barrier();
        ++S; bc = (bc == 2) ? 0 : bc + 1; bi = (bi == 2) ? 0 : bi + 1;
      }
    }
  }

  // epilogue (column mapping: tx*4+e and 256+tx*4+e)
#pragma unroll
  for (int i = 0; i < 4; ++i) {
    float inv = 1.0f / l[i];
    float4 oa, ob;
#pragma unroll
    for (int e = 0; e < 4; ++e) { oa[e] = O[i][e] * inv; ob[e] = O[i][4 + e] * inv; }
    *(float4*)(Out + (size_t)(r0 + i) * 512 + tx * 4) = oa;
    *(float4*)(Out + (size_t)(r0 + i) * 512 + 256 + tx * 4) = ob;
  }
}

// ---------------------------------------------------------------------------
// Kernel C: h = Out(8192x512) @ W1(512x512) + b1   (fp32 tiled)
// ---------------------------------------------------------------------------
__global__ __launch_bounds__(256) void mlp1_kernel(
    const float* __restrict__ X, const float* __restrict__ W1,
    const float* __restrict__ b1, float* __restrict__ Ho)
{
  __shared__ float smA[32][64];
  __shared__ float smB[64][128];
  const int t = threadIdx.x;
  const int cb = blockIdx.x;
  const int rb = blockIdx.y;
  const int col0 = cb * 128;
  const int tr = t >> 5, tc = t & 31;
  float acc[4][4] = {};
#pragma unroll 1
  for (int kc = 0; kc < 8; ++kc) {
    __syncthreads();
#pragma unroll
    for (int i = 0; i < 2; ++i) {
      int id = i * 256 + t;
      int r = id >> 4, c4 = id & 15;
      *(float4*)&smA[r][c4 * 4] =
          *(const float4*)(X + (size_t)(rb * 32 + r) * 512 + kc * 64 + c4 * 4);
    }
#pragma unroll
    for (int i = 0; i < 8; ++i) {
      int id = i * 256 + t;
      int kr = id >> 5, c4 = id & 31;
      *(float4*)&smB[kr][c4 * 4] =
          *(const float4*)(W1 + (size_t)(kc * 64 + kr) * 512 + col0 + c4 * 4);
    }
    __syncthreads();
#pragma unroll 4
    for (int k2 = 0; k2 < 64; ++k2) {
      float4 b = *(const float4*)&smB[k2][tc * 4];
      float a0 = smA[tr * 4 + 0][k2];
      float a1 = smA[tr * 4 + 1][k2];
      float a2 = smA[tr * 4 + 2][k2];
      float a3 = smA[tr * 4 + 3][k2];
#pragma unroll
      for (int j = 0; j < 4; ++j) {
        acc[0][j] += a0 * b[j];
        acc[1][j] += a1 * b[j];
        acc[2][j] += a2 * b[j];
        acc[3][j] += a3 * b[j];
      }
    }
  }
  const int r0 = rb * 32 + tr * 4;
  float4 bb = *(const float4*)(b1 + col0 + tc * 4);
#pragma unroll
  for (int ii = 0; ii < 4; ++ii) {
    float4 o;
#pragma unroll
    for (int j = 0; j < 4; ++j) o[j] = acc[ii][j] + bb[j];
    *(float4*)(Ho + (size_t)(r0 + ii) * 512 + col0 + tc * 4) = o;
  }
}

// ---------------------------------------------------------------------------
// Kernel D: per-row LayerNorm + ReLU + (512->2) head. One wave per row.
// ---------------------------------------------------------------------------
__global__ __launch_bounds__(256) void act_kernel(
    const float* __restrict__ H, const float* __restrict__ g1,
    const float* __restrict__ be1, const float* __restrict__ W2,
    const float* __restrict__ b2, float* __restrict__ act)
{
  const int lane = threadIdx.x & 63;
  const int w = threadIdx.x >> 6;
  const int row = blockIdx.x * 4 + w;
  const float* h = H + (size_t)row * 512;
  float x[8];
  *(float4*)&x[0] = *(const float4*)(h + lane * 8);
  *(float4*)&x[4] = *(const float4*)(h + lane * 8 + 4);
  float s = 0.f;
#pragma unroll
  for (int j = 0; j < 8; ++j) s += x[j];
#pragma unroll
  for (int o = 1; o < 64; o <<= 1) s += __shfl_xor(s, o);
  const float mu = s * (1.0f / 512.0f);
  float vs = 0.f;
#pragma unroll
  for (int j = 0; j < 8; ++j) { float d = x[j] - mu; vs += d * d; }
#pragma unroll
  for (int o = 1; o < 64; o <<= 1) vs += __shfl_xor(vs, o);
  const float rs = 1.0f / sqrtf(vs * (1.0f / 512.0f) + 1e-5f);
  float at = 0.f, ad = 0.f;
#pragma unroll
  for (int j = 0; j < 8; ++j) {
    int c = lane * 8 + j;
    float xn = (x[j] - mu) * rs * g1[c] + be1[c];
    xn = fmaxf(xn, 0.0f);
    at += xn * W2[2 * c];
    ad += xn * W2[2 * c + 1];
  }
#pragma unroll
  for (int o = 1; o < 64; o <<= 1) { at += __shfl_xor(at, o); ad += __shfl_xor(ad, o); }
  if (lane == 0) {
    act[row * 2 + 0] = at + b2[0];
    act[row * 2 + 1] = ad + b2[1];
  }
}

// ---------------------------------------------------------------------------
// Kernel E: 100-step bicycle model, jax op order exact (incl. per-step
// atan2(sin,cos) wrap). f_load = 0 (C_A=C_R=0).
// ---------------------------------------------------------------------------
__global__ __launch_bounds__(256) void physics_kernel(
    const float* __restrict__ obs, const float* __restrict__ act,
    float* __restrict__ out)
{
  const int row = blockIdx.x * 256 + threadIdx.x;
  const float* o = obs + (size_t)row * 128;
  float xx = o[0] * 10.0f;
  float yy = o[1] * 10.0f;
  float vx = o[2] * 10.0f;
  float vy = o[3] * 10.0f;
  float yw = o[4] * 10.0f;
  float vv = sqrtf(vx * vx + vy * vy);
  const float th = act[row * 2 + 0];
  const float de = act[row * 2 + 1];
  const float dt_s = 0.001f;
  const float inv_wb = (float)(1.0 / 2.96);
  const float td = tanf(de);
#pragma unroll 1
  for (int i = 0; i < 100; ++i) {
    vv = vv + th * dt_s;
    float s1 = sinf(yw), c1 = cosf(yw);
    xx = xx + vv * c1 * dt_s;
    yy = yy + vv * s1 * dt_s;
    yw = yw + ((vv * td) * inv_wb) * dt_s;
    yw = atan2f(sinf(yw), cosf(yw));
  }
  float cf = cosf(yw), sf = sinf(yw);
  out[row * 5 + 0] = xx * 0.1f;
  out[row * 5 + 1] = yy * 0.1f;
  out[row * 5 + 2] = vv * cf * 0.1f;
  out[row * 5 + 3] = vv * sf * 0.1f;
  out[row * 5 + 4] = yw * 0.1f;
}

// ---------------------------------------------------------------------------
extern "C" void kernel_launch(void* const* d_in, const int* in_sizes, int n_in,
                              void* d_out, int out_size, void* d_ws, size_t ws_size,
                              hipStream_t stream) {
  const float* obs = (const float*)d_in[0];
  const float* Wq  = (const float*)d_in[1];
  const float* bq  = (const float*)d_in[2];
  const float* Wk  = (const float*)d_in[3];
  const float* bk  = (const float*)d_in[4];
  const float* Wv  = (const float*)d_in[5];
  const float* bv  = (const float*)d_in[6];
  const float* W1  = (const float*)d_in[7];
  const float* b1  = (const float*)d_in[8];
  const float* g1  = (const float*)d_in[9];
  const float* be1 = (const float*)d_in[10];
  const float* W2  = (const float*)d_in[11];
  const float* b2  = (const float*)d_in[12];

  char* ws = (char*)d_ws;
  float* Qf  = (float*)(ws);                         // [0,16M)
  float* Kf  = (float*)(ws + (size_t)(16 << 20));    // [16M,32M)
  float* Vf  = (float*)(ws + (size_t)(32 << 20));    // [32M,48M)
  float* Aout= (float*)(ws + (size_t)(48 << 20));    // [48M,64M)
  float* Ho  = (float*)(ws);                         // reuse [0,16M)
  float* Act = (float*)(ws + (size_t)(16 << 20));    // reuse [16M,+64K)
  float* out = (float*)d_out;

  qkv_f32<<<dim3(12, 256), 256, 0, stream>>>(obs, Wq, bq, Wk, bk, Wv, bv, Qf, Kf, Vf);
  flash_f32<<<dim3(256), 512, 0, stream>>>(Qf, Kf, Vf, Aout);
  mlp1_kernel<<<dim3(4, 256), 256, 0, stream>>>(Aout, W1, b1, Ho);
  act_kernel<<<dim3(2048), 256, 0, stream>>>(Ho, g1, be1, W2, b2, Act);
  physics_kernel<<<dim3(32), 256, 0, stream>>>(obs, Act, out);
}

// Round 9
// 2424.730 us; speedup vs baseline: 3.5592x; 1.0235x over previous
//
#include <hip/hip_runtime.h>
#include <stdint.h>

// All-fp32 pipeline (bf16/split-bf16 fail: LN amplifies attention error x55,
// tan(delta) physics is chaotic near |delta|=pi/2 -> need fp32 delta).

typedef __attribute__((ext_vector_type(4))) float f32x4;

__device__ __forceinline__ float readlane_f(float v, int lane) {
  return __uint_as_float(__builtin_amdgcn_readlane(__float_as_uint(v), lane));
}

typedef __attribute__((address_space(3))) uint32_t lds_u32;
typedef const __attribute__((address_space(1))) uint32_t glb_u32;
__device__ __forceinline__ void gload16(const void* g, void* l) {
  // global -> LDS direct copy; LDS dest = l + lane*16 (wave-uniform l).
  __builtin_amdgcn_global_load_lds((glb_u32*)g, (lds_u32*)l, 16, 0, 0);
}

// ---------------------------------------------------------------------------
// Kernel A: fused QKV projection (fp32). obs(8192x128) @ {Wq,Wk,Wv}(128x512)+b
// ---------------------------------------------------------------------------
__global__ __launch_bounds__(256) void qkv_f32(
    const float* __restrict__ obs,
    const float* __restrict__ Wq, const float* __restrict__ bq,
    const float* __restrict__ Wk, const float* __restrict__ bk,
    const float* __restrict__ Wv, const float* __restrict__ bv,
    float* __restrict__ Qf, float* __restrict__ Kf, float* __restrict__ Vf)
{
  __shared__ float smA[32][128];
  __shared__ float smB[64][128];
  const int t  = threadIdx.x;
  const int cb = blockIdx.x;
  const int rb = blockIdx.y;
  const float* W; const float* bias; float* Op;
  if (cb < 4)      { W = Wq; bias = bq; Op = Qf; }
  else if (cb < 8) { W = Wk; bias = bk; Op = Kf; }
  else             { W = Wv; bias = bv; Op = Vf; }
  const int col0 = (cb & 3) * 128;

  {
    const float4* src = (const float4*)(obs + (size_t)rb * (32 * 128));
    float4* dst = (float4*)&smA[0][0];
#pragma unroll
    for (int i = 0; i < 4; ++i) dst[i * 256 + t] = src[i * 256 + t];
  }

  const int tr = t >> 5, tc = t & 31;
  float acc[4][4] = {};
#pragma unroll 1
  for (int kc = 0; kc < 2; ++kc) {
    __syncthreads();
#pragma unroll
    for (int i = 0; i < 8; ++i) {
      int id = i * 256 + t;
      int kr = id >> 5, c4 = id & 31;
      *(float4*)&smB[kr][c4 * 4] =
          *(const float4*)(W + (size_t)(kc * 64 + kr) * 512 + col0 + c4 * 4);
    }
    __syncthreads();
#pragma unroll 4
    for (int k2 = 0; k2 < 64; ++k2) {
      float4 b = *(const float4*)&smB[k2][tc * 4];
      float a0 = smA[tr * 4 + 0][kc * 64 + k2];
      float a1 = smA[tr * 4 + 1][kc * 64 + k2];
      float a2 = smA[tr * 4 + 2][kc * 64 + k2];
      float a3 = smA[tr * 4 + 3][kc * 64 + k2];
#pragma unroll
      for (int j = 0; j < 4; ++j) {
        acc[0][j] += a0 * b[j];
        acc[1][j] += a1 * b[j];
        acc[2][j] += a2 * b[j];
        acc[3][j] += a3 * b[j];
      }
    }
  }

  float4 bb = *(const float4*)(bias + col0 + tc * 4);
  const int r0 = rb * 32 + tr * 4;
#pragma unroll
  for (int ii = 0; ii < 4; ++ii) {
    float4 o;
#pragma unroll
    for (int j = 0; j < 4; ++j) o[j] = acc[ii][j] + bb[j];
    *(float4*)(Op + (size_t)(r0 + ii) * 512 + col0 + tc * 4) = o;
  }
}

// ---------------------------------------------------------------------------
// Kernel B: fp32 flash attention, v7.
// 256 blocks x 512 threads (8 waves). Block = 32 q-rows; wave owns 4.
// v7 change vs v6 (arithmetic-identical): V is NOT staged in LDS. PV reads V
// directly from global (per-lane-contiguous 1KB wave reads, all 8 waves hit
// the same bytes -> L1/L2-hot; V = 16MB, L3-resident). This halves LDS
// traffic (v6 was LDS-throughput-bound: ~1.3ms of b128 reads vs ~1.05ms
// VALU, non-overlapping) and halves the barrier count; PV is barrier-free
// and overlaps the 2 prefetched K-stages of the next tile.
// K staging unchanged: 16 slots/tile (256 keys x 32 d, 32KB, source-swizzled
// ^((key&7)<<4)), 3 rotating buffers, depth-2 prefetch, vmcnt(4)+s_barrier
// per slot. FMA order per accumulator identical to rounds 2-6.
// ---------------------------------------------------------------------------
#define FLASH_NSLOTS 512

__global__ __launch_bounds__(512, 2) void flash_f32(
    const float* __restrict__ Q, const float* __restrict__ K,
    const float* __restrict__ V, float* __restrict__ Out)
{
  __shared__ __align__(16) char lds[163840];   // 64KB Qlds + 3 x 32KB K bufs
  float* Qlds = (float*)lds;
  char*  bufb = lds + 65536;
  const int t  = threadIdx.x;
  const int tx = t & 63;
  const int w  = t >> 6;
  const int qrow0 = blockIdx.x * 32;
  const int r0 = qrow0 + w * 4;
  const float sc = 0.04419417382415922f;  // 1/sqrt(512)

  // ---- stage K-slot S into buffer bidx: 4 global_load_lds_dwordx4/thread --
  auto stage = [&](int S, int bidx) {
    if (S >= FLASH_NSLOTS) S = FLASH_NSLOTS - 1;  // clamp keeps vmcnt exact
    char* lb = bufb + (bidx << 15);
    const int kt = S >> 4, sub = S & 15;
    const int key_in = tx >> 3;                   // 0..7
    const int csw = ((tx & 7) ^ key_in) << 4;     // swizzled 16B slot
    const char* gb = (const char*)K + ((size_t)kt * 256) * 2048
                   + (size_t)sub * 128 + csw;
#pragma unroll
    for (int c = 0; c < 4; ++c)
      gload16(gb + (size_t)((c * 8 + w) * 8 + key_in) * 2048,
              lb + ((c * 8 + w) << 10));
  };

  // ---- prologue: Q tile + slots 0,1 ----
  {
    const char* gq = (const char*)Q + (size_t)qrow0 * 2048 + tx * 16;
#pragma unroll
    for (int c = 0; c < 8; ++c)
      gload16(gq + ((c * 8 + w) << 10), lds + ((c * 8 + w) << 10));
  }
  stage(0, 0);
  stage(1, 1);
  asm volatile("s_waitcnt vmcnt(4)" ::: "memory");  // Q + slot0 landed
  __builtin_amdgcn_s_barrier();

  float O[4][8];
#pragma unroll
  for (int i = 0; i < 4; ++i)
#pragma unroll
    for (int n = 0; n < 8; ++n) O[i][n] = 0.f;
  float m[4], l[4];
#pragma unroll
  for (int i = 0; i < 4; ++i) { m[i] = -1e30f; l[i] = 0.f; }

  int S = 0, bc = 0, bi = 2;
  const int qbase = (w * 4) * 512 + (tx & 31);
  const int kswz = (tx & 7) << 4;

#pragma unroll 1
  for (int kt = 0; kt < 32; ++kt) {
    float p[4][4];
#pragma unroll
    for (int i = 0; i < 4; ++i)
#pragma unroll
      for (int j = 0; j < 4; ++j) p[i][j] = 0.f;

    // ---- QK^T: 16 K-slots of 32 d ----
#pragma unroll 1
    for (int s = 0; s < 16; ++s) {
      stage(S + 2, bi);
      const char* kb = bufb + (bc << 15);
      float qs[4];
#pragma unroll
      for (int i = 0; i < 4; ++i) qs[i] = Qlds[qbase + i * 512 + s * 32];
#pragma unroll
      for (int u8 = 0; u8 < 8; ++u8) {
        f32x4 kv[4];
#pragma unroll
        for (int j = 0; j < 4; ++j)
          kv[j] = *(const f32x4*)(kb + ((j * 64 + tx) << 7) + ((u8 * 16) ^ kswz));
#pragma unroll
        for (int e = 0; e < 4; ++e) {
          float q0 = readlane_f(qs[0], u8 * 4 + e);
          float q1 = readlane_f(qs[1], u8 * 4 + e);
          float q2 = readlane_f(qs[2], u8 * 4 + e);
          float q3 = readlane_f(qs[3], u8 * 4 + e);
#pragma unroll
          for (int j = 0; j < 4; ++j) {
            p[0][j] = fmaf(q0, kv[j][e], p[0][j]);
            p[1][j] = fmaf(q1, kv[j][e], p[1][j]);
            p[2][j] = fmaf(q2, kv[j][e], p[2][j]);
            p[3][j] = fmaf(q3, kv[j][e], p[3][j]);
          }
        }
      }
      asm volatile("s_waitcnt vmcnt(4)" ::: "memory");
      __builtin_amdgcn_s_barrier();
      ++S; bc = (bc == 2) ? 0 : bc + 1; bi = (bi == 2) ? 0 : bi + 1;
    }

    // ---- online softmax (identical math/order to rounds 2-6) ----
#pragma unroll
    for (int i = 0; i < 4; ++i) {
      float rmax = -1e30f;
#pragma unroll
      for (int j = 0; j < 4; ++j) { p[i][j] *= sc; rmax = fmaxf(rmax, p[i][j]); }
#pragma unroll
      for (int o = 1; o < 64; o <<= 1) rmax = fmaxf(rmax, __shfl_xor(rmax, o));
      float mn = fmaxf(m[i], rmax);
      float corr = __expf(m[i] - mn);
      m[i] = mn;
      float ps = 0.f;
#pragma unroll
      for (int j = 0; j < 4; ++j) { float e = __expf(p[i][j] - mn); p[i][j] = e; ps += e; }
#pragma unroll
      for (int o = 1; o < 64; o <<= 1) ps += __shfl_xor(ps, o);
      l[i] = l[i] * corr + ps;
#pragma unroll
      for (int n = 0; n < 8; ++n) O[i][n] *= corr;
    }

    // ---- PV: V direct from global, 4-key chunks, barrier-free ----
    // (keys ascending per O element, exactly as v6's LDS version)
#pragma unroll
    for (int j = 0; j < 4; ++j) {
      float pj0 = p[0][j], pj1 = p[1][j], pj2 = p[2][j], pj3 = p[3][j];
#pragma unroll 1
      for (int kc = 0; kc < 16; ++kc) {
        const float* vbase = V + (size_t)(kt * 256 + j * 64 + kc * 4) * 512 + tx * 4;
        f32x4 va0 = *(const f32x4*)(vbase);
        f32x4 vb0 = *(const f32x4*)(vbase + 256);
        f32x4 va1 = *(const f32x4*)(vbase + 512);
        f32x4 vb1 = *(const f32x4*)(vbase + 768);
        f32x4 va2 = *(const f32x4*)(vbase + 1024);
        f32x4 vb2 = *(const f32x4*)(vbase + 1280);
        f32x4 va3 = *(const f32x4*)(vbase + 1536);
        f32x4 vb3 = *(const f32x4*)(vbase + 1792);
#pragma unroll
        for (int kk = 0; kk < 4; ++kk) {
          const f32x4 va = (kk == 0) ? va0 : (kk == 1) ? va1 : (kk == 2) ? va2 : va3;
          const f32x4 vb = (kk == 0) ? vb0 : (kk == 1) ? vb1 : (kk == 2) ? vb2 : vb3;
          float pv0 = readlane_f(pj0, kc * 4 + kk);
          float pv1 = readlane_f(pj1, kc * 4 + kk);
          float pv2 = readlane_f(pj2, kc * 4 + kk);
          float pv3 = readlane_f(pj3, kc * 4 + kk);
#pragma unroll
          for (int e = 0; e < 4; ++e) {
            O[0][e] = fmaf(pv0, va[e], O[0][e]);
            O[1][e] = fmaf(pv1, va[e], O[1][e]);
            O[2][e] = fmaf(pv2, va[e], O[2][e]);
            O[3][e] = fmaf(pv3, va[e], O[3][e]);
            O[0][4 + e] = fmaf(pv0, vb[e], O[0][4 + e]);
            O[1][4 + e] = fmaf(pv1, vb[e], O[1][4 + e]);
            O[2][4 + e] = fmaf(pv2, vb[e], O[2][4 + e]);
            O[3][4 + e] = fmaf(pv3, vb[e], O[3][4 + e]);
          }
        }
      }
    }
  }

  // epilogue (column mapping: tx*4+e and 256+tx*4+e)
#pragma unroll
  for (int i = 0; i < 4; ++i) {
    float inv = 1.0f / l[i];
    float4 oa, ob;
#pragma unroll
    for (int e = 0; e < 4; ++e) { oa[e] = O[i][e] * inv; ob[e] = O[i][4 + e] * inv; }
    *(float4*)(Out + (size_t)(r0 + i) * 512 + tx * 4) = oa;
    *(float4*)(Out + (size_t)(r0 + i) * 512 + 256 + tx * 4) = ob;
  }
}

// ---------------------------------------------------------------------------
// Kernel C: h = Out(8192x512) @ W1(512x512) + b1   (fp32 tiled)
// ---------------------------------------------------------------------------
__global__ __launch_bounds__(256) void mlp1_kernel(
    const float* __restrict__ X, const float* __restrict__ W1,
    const float* __restrict__ b1, float* __restrict__ Ho)
{
  __shared__ float smA[32][64];
  __shared__ float smB[64][128];
  const int t = threadIdx.x;
  const int cb = blockIdx.x;
  const int rb = blockIdx.y;
  const int col0 = cb * 128;
  const int tr = t >> 5, tc = t & 31;
  float acc[4][4] = {};
#pragma unroll 1
  for (int kc = 0; kc < 8; ++kc) {
    __syncthreads();
#pragma unroll
    for (int i = 0; i < 2; ++i) {
      int id = i * 256 + t;
      int r = id >> 4, c4 = id & 15;
      *(float4*)&smA[r][c4 * 4] =
          *(const float4*)(X + (size_t)(rb * 32 + r) * 512 + kc * 64 + c4 * 4);
    }
#pragma unroll
    for (int i = 0; i < 8; ++i) {
      int id = i * 256 + t;
      int kr = id >> 5, c4 = id & 31;
      *(float4*)&smB[kr][c4 * 4] =
          *(const float4*)(W1 + (size_t)(kc * 64 + kr) * 512 + col0 + c4 * 4);
    }
    __syncthreads();
#pragma unroll 4
    for (int k2 = 0; k2 < 64; ++k2) {
      float4 b = *(const float4*)&smB[k2][tc * 4];
      float a0 = smA[tr * 4 + 0][k2];
      float a1 = smA[tr * 4 + 1][k2];
      float a2 = smA[tr * 4 + 2][k2];
      float a3 = smA[tr * 4 + 3][k2];
#pragma unroll
      for (int j = 0; j < 4; ++j) {
        acc[0][j] += a0 * b[j];
        acc[1][j] += a1 * b[j];
        acc[2][j] += a2 * b[j];
        acc[3][j] += a3 * b[j];
      }
    }
  }
  const int r0 = rb * 32 + tr * 4;
  float4 bb = *(const float4*)(b1 + col0 + tc * 4);
#pragma unroll
  for (int ii = 0; ii < 4; ++ii) {
    float4 o;
#pragma unroll
    for (int j = 0; j < 4; ++j) o[j] = acc[ii][j] + bb[j];
    *(float4*)(Ho + (size_t)(r0 + ii) * 512 + col0 + tc * 4) = o;
  }
}

// ---------------------------------------------------------------------------
// Kernel D: per-row LayerNorm + ReLU + (512->2) head. One wave per row.
// ---------------------------------------------------------------------------
__global__ __launch_bounds__(256) void act_kernel(
    const float* __restrict__ H, const float* __restrict__ g1,
    const float* __restrict__ be1, const float* __restrict__ W2,
    const float* __restrict__ b2, float* __restrict__ act)
{
  const int lane = threadIdx.x & 63;
  const int w = threadIdx.x >> 6;
  const int row = blockIdx.x * 4 + w;
  const float* h = H + (size_t)row * 512;
  float x[8];
  *(float4*)&x[0] = *(const float4*)(h + lane * 8);
  *(float4*)&x[4] = *(const float4*)(h + lane * 8 + 4);
  float s = 0.f;
#pragma unroll
  for (int j = 0; j < 8; ++j) s += x[j];
#pragma unroll
  for (int o = 1; o < 64; o <<= 1) s += __shfl_xor(s, o);
  const float mu = s * (1.0f / 512.0f);
  float vs = 0.f;
#pragma unroll
  for (int j = 0; j < 8; ++j) { float d = x[j] - mu; vs += d * d; }
#pragma unroll
  for (int o = 1; o < 64; o <<= 1) vs += __shfl_xor(vs, o);
  const float rs = 1.0f / sqrtf(vs * (1.0f / 512.0f) + 1e-5f);
  float at = 0.f, ad = 0.f;
#pragma unroll
  for (int j = 0; j < 8; ++j) {
    int c = lane * 8 + j;
    float xn = (x[j] - mu) * rs * g1[c] + be1[c];
    xn = fmaxf(xn, 0.0f);
    at += xn * W2[2 * c];
    ad += xn * W2[2 * c + 1];
  }
#pragma unroll
  for (int o = 1; o < 64; o <<= 1) { at += __shfl_xor(at, o); ad += __shfl_xor(ad, o); }
  if (lane == 0) {
    act[row * 2 + 0] = at + b2[0];
    act[row * 2 + 1] = ad + b2[1];
  }
}

// ---------------------------------------------------------------------------
// Kernel E: 100-step bicycle model, jax op order exact (incl. per-step
// atan2(sin,cos) wrap). f_load = 0 (C_A=C_R=0).
// ---------------------------------------------------------------------------
__global__ __launch_bounds__(256) void physics_kernel(
    const float* __restrict__ obs, const float* __restrict__ act,
    float* __restrict__ out)
{
  const int row = blockIdx.x * 256 + threadIdx.x;
  const float* o = obs + (size_t)row * 128;
  float xx = o[0] * 10.0f;
  float yy = o[1] * 10.0f;
  float vx = o[2] * 10.0f;
  float vy = o[3] * 10.0f;
  float yw = o[4] * 10.0f;
  float vv = sqrtf(vx * vx + vy * vy);
  const float th = act[row * 2 + 0];
  const float de = act[row * 2 + 1];
  const float dt_s = 0.001f;
  const float inv_wb = (float)(1.0 / 2.96);
  const float td = tanf(de);
#pragma unroll 1
  for (int i = 0; i < 100; ++i) {
    vv = vv + th * dt_s;
    float s1 = sinf(yw), c1 = cosf(yw);
    xx = xx + vv * c1 * dt_s;
    yy = yy + vv * s1 * dt_s;
    yw = yw + ((vv * td) * inv_wb) * dt_s;
    yw = atan2f(sinf(yw), cosf(yw));
  }
  float cf = cosf(yw), sf = sinf(yw);
  out[row * 5 + 0] = xx * 0.1f;
  out[row * 5 + 1] = yy * 0.1f;
  out[row * 5 + 2] = vv * cf * 0.1f;
  out[row * 5 + 3] = vv * sf * 0.1f;
  out[row * 5 + 4] = yw * 0.1f;
}

// ---------------------------------------------------------------------------
extern "C" void kernel_launch(void* const* d_in, const int* in_sizes, int n_in,
                              void* d_out, int out_size, void* d_ws, size_t ws_size,
                              hipStream_t stream) {
  const float* obs = (const float*)d_in[0];
  const float* Wq  = (const float*)d_in[1];
  const float* bq  = (const float*)d_in[2];
  const float* Wk  = (const float*)d_in[3];
  const float* bk  = (const float*)d_in[4];
  const float* Wv  = (const float*)d_in[5];
  const float* bv  = (const float*)d_in[6];
  const float* W1  = (const float*)d_in[7];
  const float* b1  = (const float*)d_in[8];
  const float* g1  = (const float*)d_in[9];
  const float* be1 = (const float*)d_in[10];
  const float* W2  = (const float*)d_in[11];
  const float* b2  = (const float*)d_in[12];

  char* ws = (char*)d_ws;
  float* Qf  = (float*)(ws);                         // [0,16M)
  float* Kf  = (float*)(ws + (size_t)(16 << 20));    // [16M,32M)
  float* Vf  = (float*)(ws + (size_t)(32 << 20));    // [32M,48M)
  float* Aout= (float*)(ws + (size_t)(48 << 20));    // [48M,64M)
  float* Ho  = (float*)(ws);                         // reuse [0,16M)
  float* Act = (float*)(ws + (size_t)(16 << 20));    // reuse [16M,+64K)
  float* out = (float*)d_out;

  qkv_f32<<<dim3(12, 256), 256, 0, stream>>>(obs, Wq, bq, Wk, bk, Wv, bv, Qf, Kf, Vf);
  flash_f32<<<dim3(256), 512, 0, stream>>>(Qf, Kf, Vf, Aout);
  mlp1_kernel<<<dim3(4, 256), 256, 0, stream>>>(Aout, W1, b1, Ho);
  act_kernel<<<dim3(2048), 256, 0, stream>>>(Ho, g1, be1, W2, b2, Act);
  physics_kernel<<<dim3(32), 256, 0, stream>>>(obs, Act, out);
}